// Round 5
// baseline (1124.353 us; speedup 1.0000x reference)
//
#include <hip/hip_runtime.h>
#include <hip/hip_cooperative_groups.h>
#include <math.h>

namespace cg = cooperative_groups;

#define NN 10000
#define EE 160000
#define DIM 256
#define KK 512            // concatenated K = 2*DIM
#define EPS_BN 1e-5f
#define GRID 512          // 2 blocks/CU x 256 CU guaranteed at <=256 VGPR
#define NTH (GRID * 256)
#define NWAVES (GRID * 4)
#define NTILES 626        // 313 row-tiles x 2 col-halves

typedef __attribute__((ext_vector_type(8)))  short bf16x8;
typedef __attribute__((ext_vector_type(16))) float f32x16;

static __device__ __forceinline__ unsigned short f2bf(float f) {
    unsigned u = __float_as_uint(f);
    unsigned r = (u + 0x7fffu + ((u >> 16) & 1u)) >> 16;   // RTNE
    return (unsigned short)r;
}
static __device__ __forceinline__ float bflo(unsigned v) { return __uint_as_float(v << 16); }
static __device__ __forceinline__ float bfhi(unsigned v) { return __uint_as_float(v & 0xffff0000u); }
static __device__ __forceinline__ unsigned packbf(float a, float b) {
    return (unsigned)f2bf(a) | ((unsigned)f2bf(b) << 16);
}

struct Params {
    const float* x; const int* src; const int* dst;
    const float *Ws0, *Wn0, *Ws1, *Wn1, *Ws2, *Wn2;
    const float *g0, *be0, *g1, *be1, *g2, *be2;
    float* out;
    unsigned short* hcat;   // [NN][KK] bf16: left = h, right = mean
    unsigned short* zbuf;   // [NN][DIM] bf16 pre-BN
    unsigned short* wcat;   // [3][DIM][KK] bf16, [n][k] layout
    float* stats;           // [3][2*DIM]
    float* inv_deg;
    int* deg_cnt; int* row_ofs; int* cursor; int* csr_src;
};

// ================= phase bodies (shared by mono + fallback) =================

static __device__ __forceinline__ void dev_prep(int g0, int stride, const Params& P) {
    for (int g = g0; g < NN * 64; g += stride) {            // x -> hcat left (bf16)
        int r = g >> 6, c4 = (g & 63) * 4;
        float4 v = *(const float4*)(P.x + (size_t)r * DIM + c4);
        uint2 p; p.x = packbf(v.x, v.y); p.y = packbf(v.z, v.w);
        *(uint2*)(P.hcat + (size_t)r * KK + c4) = p;
    }
    for (int g = g0; g < 3 * DIM * KK; g += stride) {       // [Ws;Wn] -> wcat [n][k]
        int L = g >> 17; int i = g & 131071;
        int k = i >> 8, n = i & 255;
        const float* Ws = (L == 0) ? P.Ws0 : ((L == 1) ? P.Ws1 : P.Ws2);
        const float* Wn = (L == 0) ? P.Wn0 : ((L == 1) ? P.Wn1 : P.Wn2);
        float v = (k < DIM) ? Ws[(size_t)k * DIM + n] : Wn[(size_t)(k - DIM) * DIM + n];
        P.wcat[(size_t)L * DIM * KK + (size_t)n * KK + k] = f2bf(v);
    }
    for (int g = g0; g < NN + 6 * DIM; g += stride) {
        if (g < NN) P.deg_cnt[g] = 0;
        else P.stats[g - NN] = 0.f;
    }
}

static __device__ __forceinline__ void dev_deg(int g0, int stride, const Params& P) {
    for (int e = g0; e < EE; e += stride) atomicAdd(&P.deg_cnt[P.dst[e]], 1);
}

// one block's worth of work; every executing block computes identical values
static __device__ __forceinline__ void dev_scan(const Params& P) {
    __shared__ int wsum[4];
    int t = threadIdx.x;
    int wave = t >> 6, lane = t & 63;
    const int CH = 40;                                      // 256*40 >= NN
    int base = t * CH;
    int s = 0;
    for (int i = 0; i < CH; ++i) { int idx = base + i; if (idx < NN) s += P.deg_cnt[idx]; }
    int v = s;
    for (int off = 1; off < 64; off <<= 1) {                // wave inclusive scan
        int u = __shfl_up(v, off);
        if (lane >= off) v += u;
    }
    if (lane == 63) wsum[wave] = v;
    __syncthreads();
    int wp = 0;
    for (int i = 0; i < wave; ++i) wp += wsum[i];
    int off2 = v - s + wp;                                  // exclusive prefix
    for (int i = 0; i < CH; ++i) {
        int idx = base + i;
        if (idx < NN) {
            P.row_ofs[idx] = off2;
            P.cursor[idx]  = off2;
            int d = P.deg_cnt[idx];
            P.inv_deg[idx] = 1.0f / (float)(d > 1 ? d : 1);
            off2 += d;
        }
    }
    if (t == 255) P.row_ofs[NN] = off2;
}

static __device__ __forceinline__ void dev_fill(int g0, int stride, const Params& P) {
    for (int e = g0; e < EE; e += stride) {
        int p = atomicAdd(&P.cursor[P.dst[e]], 1);
        P.csr_src[p] = P.src[e];
    }
}

static __device__ __forceinline__ void dev_agg(int w0, int wstride, int lane, const Params& P) {
    const uint2* base = (const uint2*)P.hcat;               // row = 128 uint2
    for (int node = w0; node < NN; node += wstride) {
        int s = P.row_ofs[node], e = P.row_ofs[node + 1];
        float a0 = 0.f, a1 = 0.f, a2 = 0.f, a3 = 0.f;
        int j = s;
        for (; j + 4 <= e; j += 4) {
            int i0 = P.csr_src[j], i1 = P.csr_src[j + 1];
            int i2 = P.csr_src[j + 2], i3 = P.csr_src[j + 3];
            uint2 v0 = base[(size_t)i0 * 128 + lane];
            uint2 v1 = base[(size_t)i1 * 128 + lane];
            uint2 v2 = base[(size_t)i2 * 128 + lane];
            uint2 v3 = base[(size_t)i3 * 128 + lane];
            a0 += (bflo(v0.x) + bflo(v1.x)) + (bflo(v2.x) + bflo(v3.x));
            a1 += (bfhi(v0.x) + bfhi(v1.x)) + (bfhi(v2.x) + bfhi(v3.x));
            a2 += (bflo(v0.y) + bflo(v1.y)) + (bflo(v2.y) + bflo(v3.y));
            a3 += (bfhi(v0.y) + bfhi(v1.y)) + (bfhi(v2.y) + bfhi(v3.y));
        }
        for (; j < e; ++j) {
            uint2 v0 = base[(size_t)P.csr_src[j] * 128 + lane];
            a0 += bflo(v0.x); a1 += bfhi(v0.x); a2 += bflo(v0.y); a3 += bfhi(v0.y);
        }
        float inv = P.inv_deg[node];
        uint2 p; p.x = packbf(a0 * inv, a1 * inv); p.y = packbf(a2 * inv, a3 * inv);
        ((uint2*)P.hcat)[(size_t)node * 128 + 64 + lane] = p;
    }
}

static __device__ __forceinline__ void dev_gemm(int tile0, int tstride, int t, const Params& P,
                                                const unsigned short* wcatL, float* statsL) {
    int wave = t >> 6, lane = t & 63;
    int m = lane & 31, half = lane >> 5;
    for (int tile = tile0; tile < NTILES; tile += tstride) {
        int rowt = tile >> 1, colh = tile & 1;
        int row0 = rowt * 32;
        int colw0 = colh * 128 + wave * 32;
        int ar = row0 + m; if (ar > NN - 1) ar = NN - 1;    // clamp; stores masked
        const unsigned short* Ap = P.hcat + (size_t)ar * KK + half * 8;
        const unsigned short* Bp = wcatL + (size_t)(colw0 + m) * KK + half * 8;
        f32x16 acc;
#pragma unroll
        for (int i = 0; i < 16; ++i) acc[i] = 0.f;
#pragma unroll 8
        for (int k0 = 0; k0 < KK; k0 += 16) {
            bf16x8 a  = *(const bf16x8*)(Ap + k0);
            bf16x8 bb = *(const bf16x8*)(Bp + k0);
            acc = __builtin_amdgcn_mfma_f32_32x32x16_bf16(a, bb, acc, 0, 0, 0);
        }
        int cc = colw0 + m;
        float s = 0.f, s2 = 0.f;
#pragma unroll
        for (int reg = 0; reg < 16; ++reg) {
            int r = row0 + (reg & 3) + 8 * (reg >> 2) + 4 * half;
            if (r < NN) {
                float v = acc[reg];
                P.zbuf[(size_t)r * DIM + cc] = f2bf(v);
                s += v; s2 += v * v;
            }
        }
        s  += __shfl_down(s, 32);
        s2 += __shfl_down(s2, 32);
        if (half == 0) {
            atomicAdd(&statsL[cc], s);
            atomicAdd(&statsL[DIM + cc], s2);
        }
    }
}

static __device__ __forceinline__ void dev_norm(int b0, int bstride, int t, int act,
                                                const Params& P, const float* statsL,
                                                const float* gam, const float* bet) {
    int c8 = (t & 31) * 8;
    int rsub = t >> 5;
    float sc[8], sh[8];
#pragma unroll
    for (int i = 0; i < 8; ++i) {
        int c = c8 + i;
        float mu  = statsL[c] * (1.0f / NN);
        float var = statsL[DIM + c] * (1.0f / NN) - mu * mu;
        float k = rsqrtf(var + EPS_BN) * gam[c];
        sc[i] = k;
        sh[i] = bet[c] - mu * k;
    }
    for (int rg = b0; rg < 1250; rg += bstride) {
        int r = rg * 8 + rsub;
        uint4 v = *(const uint4*)(P.zbuf + (size_t)r * DIM + c8);
        float f[8] = {bflo(v.x), bfhi(v.x), bflo(v.y), bfhi(v.y),
                      bflo(v.z), bfhi(v.z), bflo(v.w), bfhi(v.w)};
#pragma unroll
        for (int i = 0; i < 8; ++i) f[i] = f[i] * sc[i] + sh[i];
        if (act) {
            float4 o0, o1;
            o0.x = 1.0f / (1.0f + __expf(-f[0]));
            o0.y = 1.0f / (1.0f + __expf(-f[1]));
            o0.z = 1.0f / (1.0f + __expf(-f[2]));
            o0.w = 1.0f / (1.0f + __expf(-f[3]));
            o1.x = 1.0f / (1.0f + __expf(-f[4]));
            o1.y = 1.0f / (1.0f + __expf(-f[5]));
            o1.z = 1.0f / (1.0f + __expf(-f[6]));
            o1.w = 1.0f / (1.0f + __expf(-f[7]));
            *(float4*)(P.out + (size_t)r * DIM + c8)     = o0;
            *(float4*)(P.out + (size_t)r * DIM + c8 + 4) = o1;
        } else {
            uint4 p;
            p.x = packbf(fmaxf(f[0], 0.f), fmaxf(f[1], 0.f));
            p.y = packbf(fmaxf(f[2], 0.f), fmaxf(f[3], 0.f));
            p.z = packbf(fmaxf(f[4], 0.f), fmaxf(f[5], 0.f));
            p.w = packbf(fmaxf(f[6], 0.f), fmaxf(f[7], 0.f));
            *(uint4*)(P.hcat + (size_t)r * KK + c8) = p;
        }
    }
}

// ================= mono cooperative kernel =================
__global__ __launch_bounds__(256, 2) void k_all(Params P) {
    cg::grid_group grid = cg::this_grid();
    const int t = threadIdx.x;
    const int b = blockIdx.x;
    const int g0 = b * 256 + t;
    const int lane = t & 63, wave = t >> 6;
    const int gw = b * 4 + wave;

    dev_prep(g0, NTH, P);
    grid.sync();
    dev_deg(g0, NTH, P);
    grid.sync();
    dev_scan(P);                      // redundant per block, identical values
    grid.sync();
    dev_fill(g0, NTH, P);
    grid.sync();

    for (int L = 0; L < 3; ++L) {
        const unsigned short* wcatL = P.wcat + (size_t)L * DIM * KK;
        float* statsL = P.stats + L * 2 * DIM;
        const float* gamL = (L == 0) ? P.g0 : ((L == 1) ? P.g1 : P.g2);
        const float* betL = (L == 0) ? P.be0 : ((L == 1) ? P.be1 : P.be2);
        dev_agg(gw, NWAVES, lane, P);
        grid.sync();
        dev_gemm(b, GRID, t, P, wcatL, statsL);
        grid.sync();
        dev_norm(b, GRID, t, (L == 2) ? 1 : 0, P, statsL, gamL, betL);
        if (L < 2) grid.sync();
    }
}

// ================= fallback kernels =================
__global__ __launch_bounds__(256) void kf_prep(Params P) {
    dev_prep(blockIdx.x * 256 + threadIdx.x, gridDim.x * 256, P);
}
__global__ __launch_bounds__(256) void kf_deg(Params P) {
    dev_deg(blockIdx.x * 256 + threadIdx.x, gridDim.x * 256, P);
}
__global__ __launch_bounds__(256) void kf_scan(Params P) { dev_scan(P); }   // 1 block
__global__ __launch_bounds__(256) void kf_fill(Params P) {
    dev_fill(blockIdx.x * 256 + threadIdx.x, gridDim.x * 256, P);
}
__global__ __launch_bounds__(256) void kf_agg(Params P) {
    int t = threadIdx.x;
    dev_agg(blockIdx.x * 4 + (t >> 6), gridDim.x * 4, t & 63, P);
}
__global__ __launch_bounds__(256) void kf_gemm(Params P, int L) {
    dev_gemm(blockIdx.x, gridDim.x, threadIdx.x, P,
             P.wcat + (size_t)L * DIM * KK, P.stats + L * 2 * DIM);
}
__global__ __launch_bounds__(256) void kf_norm(Params P, int L) {
    const float* gamL = (L == 0) ? P.g0 : ((L == 1) ? P.g1 : P.g2);
    const float* betL = (L == 0) ? P.be0 : ((L == 1) ? P.be1 : P.be2);
    dev_norm(blockIdx.x, gridDim.x, threadIdx.x, (L == 2) ? 1 : 0,
             P, P.stats + L * 2 * DIM, gamL, betL);
}

extern "C" void kernel_launch(void* const* d_in, const int* in_sizes, int n_in,
                              void* d_out, int out_size, void* d_ws, size_t ws_size,
                              hipStream_t stream) {
    Params P;
    P.x   = (const float*)d_in[0];
    P.src = (const int*)d_in[1];
    P.dst = (const int*)d_in[2];
    P.Ws0 = (const float*)d_in[3];  P.Wn0 = (const float*)d_in[4];
    P.g0  = (const float*)d_in[6];  P.be0 = (const float*)d_in[7];
    P.Ws1 = (const float*)d_in[8];  P.Wn1 = (const float*)d_in[9];
    P.g1  = (const float*)d_in[11]; P.be1 = (const float*)d_in[12];
    P.Ws2 = (const float*)d_in[13]; P.Wn2 = (const float*)d_in[14];
    P.g2  = (const float*)d_in[16]; P.be2 = (const float*)d_in[17];
    P.out = (float*)d_out;

    char* ws = (char*)d_ws;
    size_t off = 0;
    P.hcat = (unsigned short*)(ws + off); off += (size_t)NN * KK * 2;        // 10.24 MB
    P.zbuf = (unsigned short*)(ws + off); off += (size_t)NN * DIM * 2;       // 5.12 MB
    P.wcat = (unsigned short*)(ws + off); off += (size_t)3 * DIM * KK * 2;   // 0.79 MB
    P.stats   = (float*)(ws + off); off += 3 * 2 * DIM * sizeof(float);
    P.inv_deg = (float*)(ws + off); off += (size_t)NN * 4;
    P.deg_cnt = (int*)(ws + off); off += (size_t)NN * 4;
    P.row_ofs = (int*)(ws + off); off += (size_t)(NN + 1) * 4; off = (off + 255) & ~(size_t)255;
    P.cursor  = (int*)(ws + off); off += (size_t)NN * 4;
    P.csr_src = (int*)(ws + off); off += (size_t)EE * 4;
    (void)ws_size;

    // occupancy-gated cooperative launch (deterministic every call)
    int nb = 0;
    hipError_t oe = hipOccupancyMaxActiveBlocksPerMultiprocessor(&nb, (const void*)k_all, 256, 0);
    if (oe == hipSuccess && nb * 256 >= GRID) {
        void* kargs[] = { (void*)&P };
        hipError_t le = hipLaunchCooperativeKernel((const void*)k_all, dim3(GRID), dim3(256),
                                                   kargs, 0, stream);
        if (le == hipSuccess) return;
        (void)hipGetLastError();     // clear error state, fall through
    }

    // fallback: proven multi-kernel pipeline
    kf_prep<<<1024, 256, 0, stream>>>(P);
    kf_deg<<<(EE + 255) / 256, 256, 0, stream>>>(P);
    kf_scan<<<1, 256, 0, stream>>>(P);
    kf_fill<<<(EE + 255) / 256, 256, 0, stream>>>(P);
    for (int L = 0; L < 3; ++L) {
        kf_agg<<<2500, 256, 0, stream>>>(P);
        kf_gemm<<<NTILES, 256, 0, stream>>>(P, L);
        kf_norm<<<1250, 256, 0, stream>>>(P, L);
    }
}

// Round 6
// 288.563 us; speedup vs baseline: 3.8964x; 3.8964x over previous
//
#include <hip/hip_runtime.h>
#include <math.h>

#define NN 10000
#define EE 160000
#define DIM 256
#define KK 512            // concatenated K = 2*DIM
#define EPS_BN 1e-5f
#define NTILES 626        // 313 row-tiles x 2 col-halves

typedef __attribute__((ext_vector_type(8)))  short bf16x8;
typedef __attribute__((ext_vector_type(16))) float f32x16;

static __device__ __forceinline__ unsigned short f2bf(float f) {
    unsigned u = __float_as_uint(f);
    unsigned r = (u + 0x7fffu + ((u >> 16) & 1u)) >> 16;   // RTNE
    return (unsigned short)r;
}
static __device__ __forceinline__ float bflo(unsigned v) { return __uint_as_float(v << 16); }
static __device__ __forceinline__ float bfhi(unsigned v) { return __uint_as_float(v & 0xffff0000u); }
static __device__ __forceinline__ unsigned packbf(float a, float b) {
    return (unsigned)f2bf(a) | ((unsigned)f2bf(b) << 16);
}

struct Params {
    const float* x; const int* src; const int* dst;
    const float *Ws0, *Wn0, *Ws1, *Wn1, *Ws2, *Wn2;
    const float *g0, *be0, *g1, *be1, *g2, *be2;
    float* out;
    unsigned short* hcat;   // [NN][KK] bf16: left = h, right = mean  (row = 64 uint4)
    unsigned short* zbuf;   // [NN][DIM] bf16 pre-BN                  (row = 32 uint4)
    unsigned short* wcat;   // [3][DIM][KK] bf16, [n][k] layout
    float* stats;           // [3][2*DIM]
    float* inv_deg;
    int* deg_cnt; int* row_ofs; int* cursor; int* csr_src;
};

static __device__ __forceinline__ void accum8(float* a, uint4 v) {
    a[0] += bflo(v.x); a[1] += bfhi(v.x);
    a[2] += bflo(v.y); a[3] += bfhi(v.y);
    a[4] += bflo(v.z); a[5] += bfhi(v.z);
    a[6] += bflo(v.w); a[7] += bfhi(v.w);
}
static __device__ __forceinline__ void accum8n(float* a, uint4 v,
                                               const float* sc, const float* sh) {
    a[0] += fmaxf(bflo(v.x) * sc[0] + sh[0], 0.f);
    a[1] += fmaxf(bfhi(v.x) * sc[1] + sh[1], 0.f);
    a[2] += fmaxf(bflo(v.y) * sc[2] + sh[2], 0.f);
    a[3] += fmaxf(bfhi(v.y) * sc[3] + sh[3], 0.f);
    a[4] += fmaxf(bflo(v.z) * sc[4] + sh[4], 0.f);
    a[5] += fmaxf(bfhi(v.z) * sc[5] + sh[5], 0.f);
    a[6] += fmaxf(bflo(v.w) * sc[6] + sh[6], 0.f);
    a[7] += fmaxf(bfhi(v.w) * sc[7] + sh[7], 0.f);
}

// ---------------- prep: converts + zeroing ----------------
__global__ __launch_bounds__(256) void k_prep(Params P) {
    int g0 = blockIdx.x * 256 + threadIdx.x;
    int stride = gridDim.x * 256;
    for (int g = g0; g < NN * 64; g += stride) {            // x -> hcat left (bf16)
        int r = g >> 6, c4 = (g & 63) * 4;
        float4 v = *(const float4*)(P.x + (size_t)r * DIM + c4);
        uint2 p; p.x = packbf(v.x, v.y); p.y = packbf(v.z, v.w);
        *(uint2*)(P.hcat + (size_t)r * KK + c4) = p;
    }
    for (int g = g0; g < 3 * DIM * KK; g += stride) {       // [Ws;Wn] -> wcat [n][k]
        int L = g >> 17; int i = g & 131071;
        int k = i >> 8, n = i & 255;
        const float* Ws = (L == 0) ? P.Ws0 : ((L == 1) ? P.Ws1 : P.Ws2);
        const float* Wn = (L == 0) ? P.Wn0 : ((L == 1) ? P.Wn1 : P.Wn2);
        float v = (k < DIM) ? Ws[(size_t)k * DIM + n] : Wn[(size_t)(k - DIM) * DIM + n];
        P.wcat[(size_t)L * DIM * KK + (size_t)n * KK + k] = f2bf(v);
    }
    for (int g = g0; g < NN + 6 * DIM; g += stride) {
        if (g < NN) P.deg_cnt[g] = 0;
        else P.stats[g - NN] = 0.f;
    }
}

// ---------------- degree histogram ----------------
__global__ __launch_bounds__(256) void k_deg(Params P) {
    int e = blockIdx.x * 256 + threadIdx.x;
    if (e < EE) atomicAdd(&P.deg_cnt[P.dst[e]], 1);
}

// ---------------- exclusive scan (1 block) ----------------
__global__ __launch_bounds__(256) void k_scan(Params P) {
    __shared__ int wsum[4];
    int t = threadIdx.x;
    int wave = t >> 6, lane = t & 63;
    const int CH = 40;                                      // 256*40 >= NN
    int base = t * CH;
    int s = 0;
    for (int i = 0; i < CH; ++i) { int idx = base + i; if (idx < NN) s += P.deg_cnt[idx]; }
    int v = s;
    for (int off = 1; off < 64; off <<= 1) {                // wave inclusive scan
        int u = __shfl_up(v, off);
        if (lane >= off) v += u;
    }
    if (lane == 63) wsum[wave] = v;
    __syncthreads();
    int wp = 0;
    for (int i = 0; i < wave; ++i) wp += wsum[i];
    int off2 = v - s + wp;                                  // exclusive prefix
    for (int i = 0; i < CH; ++i) {
        int idx = base + i;
        if (idx < NN) {
            P.row_ofs[idx] = off2;
            P.cursor[idx]  = off2;
            int d = P.deg_cnt[idx];
            P.inv_deg[idx] = 1.0f / (float)(d > 1 ? d : 1);
            off2 += d;
        }
    }
    if (t == 255) P.row_ofs[NN] = off2;
}

// ---------------- CSR fill ----------------
__global__ __launch_bounds__(256) void k_fill(Params P) {
    int e = blockIdx.x * 256 + threadIdx.x;
    if (e < EE) {
        int p = atomicAdd(&P.cursor[P.dst[e]], 1);
        P.csr_src[p] = P.src[e];
    }
}

// ---------------- aggregation (wave/node, half-wave/edge, uint4 rows) ----------
// L==0: gather bf16 h from hcat-left (stride 64 uint4).
// L>0 : gather raw z from zbuf (stride 32 uint4), fuse BN(L-1) affine + relu
//       per element; also normalize own row into hcat-left for the GEMM.
__global__ __launch_bounds__(256) void k_agg(Params P, int L) {
    int t = threadIdx.x;
    int wave = t >> 6, lane = t & 63;
    int h = lane >> 5, l = lane & 31;                       // half-wave, 32-lane id
    float sc[8], sh[8];
    if (L > 0) {
        const float* st = P.stats + (L - 1) * 2 * DIM;
        const float* gam = (L == 1) ? P.g0 : P.g1;
        const float* bet = (L == 1) ? P.be0 : P.be1;
#pragma unroll
        for (int i = 0; i < 8; ++i) {
            int c = l * 8 + i;
            float mu  = st[c] * (1.0f / NN);
            float var = st[DIM + c] * (1.0f / NN) - mu * mu;
            float k = rsqrtf(var + EPS_BN) * gam[c];
            sc[i] = k;
            sh[i] = bet[c] - mu * k;
        }
    }
    const uint4* zsrc = (const uint4*)P.zbuf;               // stride 32
    const uint4* hsrc = (const uint4*)P.hcat;               // stride 64
    uint4* hdst = (uint4*)P.hcat;

    int node = blockIdx.x * 4 + wave;                       // grid 2500 -> exact
    int s = P.row_ofs[node], e = P.row_ofs[node + 1];
    float a[8] = {0, 0, 0, 0, 0, 0, 0, 0};

    if (L > 0 && h == 0) {                                  // own-row normalize
        uint4 z = zsrc[(size_t)node * 32 + l];
        uint4 p;
        p.x = packbf(fmaxf(bflo(z.x) * sc[0] + sh[0], 0.f),
                     fmaxf(bfhi(z.x) * sc[1] + sh[1], 0.f));
        p.y = packbf(fmaxf(bflo(z.y) * sc[2] + sh[2], 0.f),
                     fmaxf(bfhi(z.y) * sc[3] + sh[3], 0.f));
        p.z = packbf(fmaxf(bflo(z.z) * sc[4] + sh[4], 0.f),
                     fmaxf(bfhi(z.z) * sc[5] + sh[5], 0.f));
        p.w = packbf(fmaxf(bflo(z.w) * sc[6] + sh[6], 0.f),
                     fmaxf(bfhi(z.w) * sc[7] + sh[7], 0.f));
        hdst[(size_t)node * 64 + l] = p;
    }

    int j = s + h;                                          // half-waves interleave edges
    if (L == 0) {
        for (; j + 6 < e; j += 8) {
            int i0 = P.csr_src[j],     i1 = P.csr_src[j + 2];
            int i2 = P.csr_src[j + 4], i3 = P.csr_src[j + 6];
            uint4 v0 = hsrc[(size_t)i0 * 64 + l];
            uint4 v1 = hsrc[(size_t)i1 * 64 + l];
            uint4 v2 = hsrc[(size_t)i2 * 64 + l];
            uint4 v3 = hsrc[(size_t)i3 * 64 + l];
            accum8(a, v0); accum8(a, v1); accum8(a, v2); accum8(a, v3);
        }
        for (; j < e; j += 2) accum8(a, hsrc[(size_t)P.csr_src[j] * 64 + l]);
    } else {
        for (; j + 6 < e; j += 8) {
            int i0 = P.csr_src[j],     i1 = P.csr_src[j + 2];
            int i2 = P.csr_src[j + 4], i3 = P.csr_src[j + 6];
            uint4 v0 = zsrc[(size_t)i0 * 32 + l];
            uint4 v1 = zsrc[(size_t)i1 * 32 + l];
            uint4 v2 = zsrc[(size_t)i2 * 32 + l];
            uint4 v3 = zsrc[(size_t)i3 * 32 + l];
            accum8n(a, v0, sc, sh); accum8n(a, v1, sc, sh);
            accum8n(a, v2, sc, sh); accum8n(a, v3, sc, sh);
        }
        for (; j < e; j += 2) accum8n(a, zsrc[(size_t)P.csr_src[j] * 32 + l], sc, sh);
    }
#pragma unroll
    for (int i = 0; i < 8; ++i) a[i] += __shfl_xor(a[i], 32);
    if (h == 0) {
        float inv = P.inv_deg[node];
        uint4 p;
        p.x = packbf(a[0] * inv, a[1] * inv);
        p.y = packbf(a[2] * inv, a[3] * inv);
        p.z = packbf(a[4] * inv, a[5] * inv);
        p.w = packbf(a[6] * inv, a[7] * inv);
        hdst[(size_t)node * 64 + 32 + l] = p;               // mean -> right half
    }
}

// ---------------- MFMA GEMM: z = hcat @ wcat[L], + column stats ----------------
// grid = 626 blocks; block = 32 rows x 256 cols; wave = one 32x32x16-MFMA chain.
__global__ __launch_bounds__(256) void k_gemm(Params P, int L) {
    const unsigned short* wcatL = P.wcat + (size_t)L * DIM * KK;
    float* statsL = P.stats + L * 2 * DIM;
    int t = threadIdx.x;
    int wave = t >> 6, lane = t & 63;
    int m = lane & 31, half = lane >> 5;
    int tile = blockIdx.x;
    int rowt = tile >> 1, colh = tile & 1;
    int row0 = rowt * 32;
    int colw0 = colh * 128 + wave * 32;
    int ar = row0 + m; if (ar > NN - 1) ar = NN - 1;        // clamp; stores masked
    const unsigned short* Ap = P.hcat + (size_t)ar * KK + half * 8;
    const unsigned short* Bp = wcatL + (size_t)(colw0 + m) * KK + half * 8;
    f32x16 acc;
#pragma unroll
    for (int i = 0; i < 16; ++i) acc[i] = 0.f;
#pragma unroll 8
    for (int k0 = 0; k0 < KK; k0 += 16) {
        bf16x8 av = *(const bf16x8*)(Ap + k0);
        bf16x8 bv = *(const bf16x8*)(Bp + k0);
        acc = __builtin_amdgcn_mfma_f32_32x32x16_bf16(av, bv, acc, 0, 0, 0);
    }
    int cc = colw0 + m;
    float s = 0.f, s2 = 0.f;
#pragma unroll
    for (int reg = 0; reg < 16; ++reg) {
        int r = row0 + (reg & 3) + 8 * (reg >> 2) + 4 * half;
        if (r < NN) {
            float v = acc[reg];
            P.zbuf[(size_t)r * DIM + cc] = f2bf(v);
            s += v; s2 += v * v;
        }
    }
    s  += __shfl_down(s, 32);
    s2 += __shfl_down(s2, 32);
    if (half == 0) {
        atomicAdd(&statsL[cc], s);
        atomicAdd(&statsL[DIM + cc], s2);
    }
}

// ---------------- final BN + sigmoid -> out (fp32) ----------------
__global__ __launch_bounds__(256) void k_norm(Params P) {
    const float* statsL = P.stats + 2 * 2 * DIM;
    int t = threadIdx.x;
    int c8 = (t & 31) * 8;
    int r = blockIdx.x * 8 + (t >> 5);                      // grid 1250
    float sc[8], sh[8];
#pragma unroll
    for (int i = 0; i < 8; ++i) {
        int c = c8 + i;
        float mu  = statsL[c] * (1.0f / NN);
        float var = statsL[DIM + c] * (1.0f / NN) - mu * mu;
        float k = rsqrtf(var + EPS_BN) * P.g2[c];
        sc[i] = k;
        sh[i] = P.be2[c] - mu * k;
    }
    uint4 v = *(const uint4*)(P.zbuf + (size_t)r * DIM + c8);
    float f[8] = {bflo(v.x), bfhi(v.x), bflo(v.y), bfhi(v.y),
                  bflo(v.z), bfhi(v.z), bflo(v.w), bfhi(v.w)};
#pragma unroll
    for (int i = 0; i < 8; ++i) f[i] = f[i] * sc[i] + sh[i];
    float4 o0, o1;
    o0.x = 1.0f / (1.0f + __expf(-f[0]));
    o0.y = 1.0f / (1.0f + __expf(-f[1]));
    o0.z = 1.0f / (1.0f + __expf(-f[2]));
    o0.w = 1.0f / (1.0f + __expf(-f[3]));
    o1.x = 1.0f / (1.0f + __expf(-f[4]));
    o1.y = 1.0f / (1.0f + __expf(-f[5]));
    o1.z = 1.0f / (1.0f + __expf(-f[6]));
    o1.w = 1.0f / (1.0f + __expf(-f[7]));
    *(float4*)(P.out + (size_t)r * DIM + c8)     = o0;
    *(float4*)(P.out + (size_t)r * DIM + c8 + 4) = o1;
}

extern "C" void kernel_launch(void* const* d_in, const int* in_sizes, int n_in,
                              void* d_out, int out_size, void* d_ws, size_t ws_size,
                              hipStream_t stream) {
    Params P;
    P.x   = (const float*)d_in[0];
    P.src = (const int*)d_in[1];
    P.dst = (const int*)d_in[2];
    P.Ws0 = (const float*)d_in[3];  P.Wn0 = (const float*)d_in[4];
    P.g0  = (const float*)d_in[6];  P.be0 = (const float*)d_in[7];
    P.Ws1 = (const float*)d_in[8];  P.Wn1 = (const float*)d_in[9];
    P.g1  = (const float*)d_in[11]; P.be1 = (const float*)d_in[12];
    P.Ws2 = (const float*)d_in[13]; P.Wn2 = (const float*)d_in[14];
    P.g2  = (const float*)d_in[16]; P.be2 = (const float*)d_in[17];
    P.out = (float*)d_out;

    char* ws = (char*)d_ws;
    size_t off = 0;
    P.hcat = (unsigned short*)(ws + off); off += (size_t)NN * KK * 2;        // 10.24 MB
    P.zbuf = (unsigned short*)(ws + off); off += (size_t)NN * DIM * 2;       // 5.12 MB
    P.wcat = (unsigned short*)(ws + off); off += (size_t)3 * DIM * KK * 2;   // 0.79 MB
    P.stats   = (float*)(ws + off); off += 3 * 2 * DIM * sizeof(float);
    P.inv_deg = (float*)(ws + off); off += (size_t)NN * 4;
    P.deg_cnt = (int*)(ws + off); off += (size_t)NN * 4;
    P.row_ofs = (int*)(ws + off); off += (size_t)(NN + 1) * 4; off = (off + 255) & ~(size_t)255;
    P.cursor  = (int*)(ws + off); off += (size_t)NN * 4;
    P.csr_src = (int*)(ws + off); off += (size_t)EE * 4;
    (void)ws_size;

    k_prep<<<1024, 256, 0, stream>>>(P);
    k_deg<<<(EE + 255) / 256, 256, 0, stream>>>(P);
    k_scan<<<1, 256, 0, stream>>>(P);
    k_fill<<<(EE + 255) / 256, 256, 0, stream>>>(P);
    for (int L = 0; L < 3; ++L) {
        k_agg<<<NN / 4, 256, 0, stream>>>(P, L);
        k_gemm<<<NTILES, 256, 0, stream>>>(P, L);
    }
    k_norm<<<NN / 8, 256, 0, stream>>>(P);
}

// Round 9
// 241.591 us; speedup vs baseline: 4.6540x; 1.1944x over previous
//
#include <hip/hip_runtime.h>
#include <math.h>

#define NN 10000
#define EE 160000
#define DIM 256
#define KK 512            // concatenated K = 2*DIM
#define CAP 128           // bucket capacity (max deg ~45 for mean-16 degrees)
#define EPS_BN 1e-5f
#define NTILES 626        // 313 row-tiles x 2 col-halves

typedef __attribute__((ext_vector_type(8)))  short bf16x8;
typedef __attribute__((ext_vector_type(16))) float f32x16;

static __device__ __forceinline__ unsigned short f2bf(float f) {
    unsigned u = __float_as_uint(f);
    unsigned r = (u + 0x7fffu + ((u >> 16) & 1u)) >> 16;   // RTNE
    return (unsigned short)r;
}
static __device__ __forceinline__ float bflo(unsigned v) { return __uint_as_float(v << 16); }
static __device__ __forceinline__ float bfhi(unsigned v) { return __uint_as_float(v & 0xffff0000u); }
static __device__ __forceinline__ unsigned packbf(float a, float b) {
    return (unsigned)f2bf(a) | ((unsigned)f2bf(b) << 16);
}

struct Params {
    const float* x; const int* src; const int* dst;
    const float *Ws0, *Wn0, *Ws1, *Wn1, *Ws2, *Wn2;
    const float *g0, *be0, *g1, *be1, *g2, *be2;
    float* out;
    unsigned short* hcat;   // [NN][KK] bf16: left = h, right = mean (row = 64 uint4)
    unsigned short* zbuf;   // [NN][DIM] bf16 pre-BN z              (row = 32 uint4)
    unsigned short* wcat;   // [3][DIM][KK] bf16, [n][k]
    float* stats;           // [3][2*DIM]
    int* cnt;               // [NN]
    int* slots;             // [NN][CAP]
};

static __device__ __forceinline__ void accum8(float* a, uint4 v) {
    a[0] += bflo(v.x); a[1] += bfhi(v.x);
    a[2] += bflo(v.y); a[3] += bfhi(v.y);
    a[4] += bflo(v.z); a[5] += bfhi(v.z);
    a[6] += bflo(v.w); a[7] += bfhi(v.w);
}
static __device__ __forceinline__ void accum8n(float* a, uint4 v,
                                               const float* sc, const float* sh) {
    a[0] += fmaxf(bflo(v.x) * sc[0] + sh[0], 0.f);
    a[1] += fmaxf(bfhi(v.x) * sc[1] + sh[1], 0.f);
    a[2] += fmaxf(bflo(v.y) * sc[2] + sh[2], 0.f);
    a[3] += fmaxf(bfhi(v.y) * sc[3] + sh[3], 0.f);
    a[4] += fmaxf(bflo(v.z) * sc[4] + sh[4], 0.f);
    a[5] += fmaxf(bfhi(v.z) * sc[5] + sh[5], 0.f);
    a[6] += fmaxf(bflo(v.w) * sc[6] + sh[6], 0.f);
    a[7] += fmaxf(bfhi(v.w) * sc[7] + sh[7], 0.f);
}

// ---------------- prep: converts + zeroing (R6 body, hcat stride KK) ----------
__global__ __launch_bounds__(256) void k_prep(Params P) {
    int g0 = blockIdx.x * 256 + threadIdx.x;
    int stride = gridDim.x * 256;
    for (int g = g0; g < NN * 64; g += stride) {            // x -> hcat left (bf16)
        int r = g >> 6, c4 = (g & 63) * 4;
        float4 v = *(const float4*)(P.x + (size_t)r * DIM + c4);
        uint2 p; p.x = packbf(v.x, v.y); p.y = packbf(v.z, v.w);
        *(uint2*)(P.hcat + (size_t)r * KK + c4) = p;
    }
    for (int g = g0; g < 3 * DIM * KK; g += stride) {       // [Ws;Wn] -> wcat [n][k]
        int L = g >> 17; int i = g & 131071;
        int k = i >> 8, n = i & 255;
        const float* Ws = (L == 0) ? P.Ws0 : ((L == 1) ? P.Ws1 : P.Ws2);
        const float* Wn = (L == 0) ? P.Wn0 : ((L == 1) ? P.Wn1 : P.Wn2);
        float v = (k < DIM) ? Ws[(size_t)k * DIM + n] : Wn[(size_t)(k - DIM) * DIM + n];
        P.wcat[(size_t)L * DIM * KK + (size_t)n * KK + k] = f2bf(v);
    }
    for (int g = g0; g < NN + 6 * DIM; g += stride) {
        if (g < NN) P.cnt[g] = 0;
        else P.stats[g - NN] = 0.f;
    }
}

// ---------------- bucket build (component under test) ----------------
__global__ __launch_bounds__(256) void k_bucket(Params P) {
    int e = blockIdx.x * 256 + threadIdx.x;
    if (e < EE) {
        int d = P.dst[e];
        int p = atomicAdd(&P.cnt[d], 1);
        if (p < CAP) P.slots[(size_t)d * CAP + p] = P.src[e];
    }
}

// ---------------- aggregation (R6 body; CSR reads -> slot reads) ----------
// wave/node, half-wave/edge, uint4 rows. L==0: gather from hcat-left.
// L>0: gather raw z from zbuf + fused BN(L-1) affine + relu; also
// normalize own row into hcat-left. Mean -> hcat right half.
__global__ __launch_bounds__(256) void k_agg(Params P, int L) {
    int t = threadIdx.x;
    int wave = t >> 6, lane = t & 63;
    int h = lane >> 5, l = lane & 31;
    float sc[8], sh[8];
    if (L > 0) {
        const float* st = P.stats + (L - 1) * 2 * DIM;
        const float* gam = (L == 1) ? P.g0 : P.g1;
        const float* bet = (L == 1) ? P.be0 : P.be1;
#pragma unroll
        for (int i = 0; i < 8; ++i) {
            int c = l * 8 + i;
            float mu  = st[c] * (1.0f / NN);
            float var = st[DIM + c] * (1.0f / NN) - mu * mu;
            float k = rsqrtf(var + EPS_BN) * gam[c];
            sc[i] = k;
            sh[i] = bet[c] - mu * k;
        }
    }
    const uint4* zsrc = (const uint4*)P.zbuf;               // stride 32
    const uint4* hsrc = (const uint4*)P.hcat;               // stride 64
    uint4* hdst = (uint4*)P.hcat;

    int node = blockIdx.x * 4 + wave;                       // grid 2500 -> exact
    int cnt = P.cnt[node]; if (cnt > CAP) cnt = CAP;
    const int* sl = P.slots + (size_t)node * CAP;
    float a[8] = {0, 0, 0, 0, 0, 0, 0, 0};

    if (L > 0 && h == 0) {                                  // own-row normalize
        uint4 z = zsrc[(size_t)node * 32 + l];
        uint4 p;
        p.x = packbf(fmaxf(bflo(z.x) * sc[0] + sh[0], 0.f),
                     fmaxf(bfhi(z.x) * sc[1] + sh[1], 0.f));
        p.y = packbf(fmaxf(bflo(z.y) * sc[2] + sh[2], 0.f),
                     fmaxf(bfhi(z.y) * sc[3] + sh[3], 0.f));
        p.z = packbf(fmaxf(bflo(z.z) * sc[4] + sh[4], 0.f),
                     fmaxf(bfhi(z.z) * sc[5] + sh[5], 0.f));
        p.w = packbf(fmaxf(bflo(z.w) * sc[6] + sh[6], 0.f),
                     fmaxf(bfhi(z.w) * sc[7] + sh[7], 0.f));
        hdst[(size_t)node * 64 + l] = p;
    }

    int j = h;                                              // half-waves interleave edges
    if (L == 0) {
        for (; j + 6 < cnt; j += 8) {
            int i0 = sl[j],     i1 = sl[j + 2];
            int i2 = sl[j + 4], i3 = sl[j + 6];
            uint4 v0 = hsrc[(size_t)i0 * 64 + l];
            uint4 v1 = hsrc[(size_t)i1 * 64 + l];
            uint4 v2 = hsrc[(size_t)i2 * 64 + l];
            uint4 v3 = hsrc[(size_t)i3 * 64 + l];
            accum8(a, v0); accum8(a, v1); accum8(a, v2); accum8(a, v3);
        }
        for (; j < cnt; j += 2) accum8(a, hsrc[(size_t)sl[j] * 64 + l]);
    } else {
        for (; j + 6 < cnt; j += 8) {
            int i0 = sl[j],     i1 = sl[j + 2];
            int i2 = sl[j + 4], i3 = sl[j + 6];
            uint4 v0 = zsrc[(size_t)i0 * 32 + l];
            uint4 v1 = zsrc[(size_t)i1 * 32 + l];
            uint4 v2 = zsrc[(size_t)i2 * 32 + l];
            uint4 v3 = zsrc[(size_t)i3 * 32 + l];
            accum8n(a, v0, sc, sh); accum8n(a, v1, sc, sh);
            accum8n(a, v2, sc, sh); accum8n(a, v3, sc, sh);
        }
        for (; j < cnt; j += 2) accum8n(a, zsrc[(size_t)sl[j] * 32 + l], sc, sh);
    }
#pragma unroll
    for (int q = 0; q < 8; ++q) a[q] += __shfl_xor(a[q], 32);
    if (h == 0) {
        float inv = 1.0f / (float)(cnt > 1 ? cnt : 1);
        uint4 p;
        p.x = packbf(a[0] * inv, a[1] * inv);
        p.y = packbf(a[2] * inv, a[3] * inv);
        p.z = packbf(a[4] * inv, a[5] * inv);
        p.w = packbf(a[6] * inv, a[7] * inv);
        hdst[(size_t)node * 64 + 32 + l] = p;               // mean -> right half
    }
}

// ---------------- MFMA GEMM (R6 body, verbatim) ----------------
// grid = 626; block = 32 rows x 256 cols; wave = one 32x32x16 MFMA chain.
__global__ __launch_bounds__(256) void k_gemm(Params P, int L) {
    const unsigned short* wcatL = P.wcat + (size_t)L * DIM * KK;
    float* statsL = P.stats + L * 2 * DIM;
    int t = threadIdx.x;
    int wave = t >> 6, lane = t & 63;
    int m = lane & 31, half = lane >> 5;
    int tile = blockIdx.x;
    int rowt = tile >> 1, colh = tile & 1;
    int row0 = rowt * 32;
    int colw0 = colh * 128 + wave * 32;
    int ar = row0 + m; if (ar > NN - 1) ar = NN - 1;        // clamp; stores masked
    const unsigned short* Ap = P.hcat + (size_t)ar * KK + half * 8;
    const unsigned short* Bp = wcatL + (size_t)(colw0 + m) * KK + half * 8;
    f32x16 acc;
#pragma unroll
    for (int i = 0; i < 16; ++i) acc[i] = 0.f;
#pragma unroll 8
    for (int k0 = 0; k0 < KK; k0 += 16) {
        bf16x8 av = *(const bf16x8*)(Ap + k0);
        bf16x8 bv = *(const bf16x8*)(Bp + k0);
        acc = __builtin_amdgcn_mfma_f32_32x32x16_bf16(av, bv, acc, 0, 0, 0);
    }
    int cc = colw0 + m;
    float s = 0.f, s2 = 0.f;
#pragma unroll
    for (int reg = 0; reg < 16; ++reg) {
        int r = row0 + (reg & 3) + 8 * (reg >> 2) + 4 * half;
        if (r < NN) {
            float v = acc[reg];
            P.zbuf[(size_t)r * DIM + cc] = f2bf(v);
            s += v; s2 += v * v;
        }
    }
    s  += __shfl_down(s, 32);
    s2 += __shfl_down(s2, 32);
    if (half == 0) {
        atomicAdd(&statsL[cc], s);
        atomicAdd(&statsL[DIM + cc], s2);
    }
}

// ---------------- final BN + sigmoid -> out (R6 body) ----------------
__global__ __launch_bounds__(256) void k_norm(Params P) {
    const float* statsL = P.stats + 2 * 2 * DIM;
    int t = threadIdx.x;
    int c8 = (t & 31) * 8;
    int r = blockIdx.x * 8 + (t >> 5);                      // grid 1250
    float sc[8], sh[8];
#pragma unroll
    for (int i = 0; i < 8; ++i) {
        int c = c8 + i;
        float mu  = statsL[c] * (1.0f / NN);
        float var = statsL[DIM + c] * (1.0f / NN) - mu * mu;
        float k = rsqrtf(var + EPS_BN) * P.g2[c];
        sc[i] = k;
        sh[i] = P.be2[c] - mu * k;
    }
    uint4 v = *(const uint4*)(P.zbuf + (size_t)r * DIM + c8);
    float f[8] = {bflo(v.x), bfhi(v.x), bflo(v.y), bfhi(v.y),
                  bflo(v.z), bfhi(v.z), bflo(v.w), bfhi(v.w)};
#pragma unroll
    for (int i = 0; i < 8; ++i) f[i] = f[i] * sc[i] + sh[i];
    float4 o0, o1;
    o0.x = 1.0f / (1.0f + __expf(-f[0]));
    o0.y = 1.0f / (1.0f + __expf(-f[1]));
    o0.z = 1.0f / (1.0f + __expf(-f[2]));
    o0.w = 1.0f / (1.0f + __expf(-f[3]));
    o1.x = 1.0f / (1.0f + __expf(-f[4]));
    o1.y = 1.0f / (1.0f + __expf(-f[5]));
    o1.z = 1.0f / (1.0f + __expf(-f[6]));
    o1.w = 1.0f / (1.0f + __expf(-f[7]));
    *(float4*)(P.out + (size_t)r * DIM + c8)     = o0;
    *(float4*)(P.out + (size_t)r * DIM + c8 + 4) = o1;
}

extern "C" void kernel_launch(void* const* d_in, const int* in_sizes, int n_in,
                              void* d_out, int out_size, void* d_ws, size_t ws_size,
                              hipStream_t stream) {
    Params P;
    P.x   = (const float*)d_in[0];
    P.src = (const int*)d_in[1];
    P.dst = (const int*)d_in[2];
    P.Ws0 = (const float*)d_in[3];  P.Wn0 = (const float*)d_in[4];
    P.g0  = (const float*)d_in[6];  P.be0 = (const float*)d_in[7];
    P.Ws1 = (const float*)d_in[8];  P.Wn1 = (const float*)d_in[9];
    P.g1  = (const float*)d_in[11]; P.be1 = (const float*)d_in[12];
    P.Ws2 = (const float*)d_in[13]; P.Wn2 = (const float*)d_in[14];
    P.g2  = (const float*)d_in[16]; P.be2 = (const float*)d_in[17];
    P.out = (float*)d_out;

    char* ws = (char*)d_ws;
    size_t off = 0;
    P.hcat = (unsigned short*)(ws + off); off += (size_t)NN * KK * 2;        // 10.24 MB
    P.zbuf = (unsigned short*)(ws + off); off += (size_t)NN * DIM * 2;       // 5.12 MB
    P.wcat = (unsigned short*)(ws + off); off += (size_t)3 * DIM * KK * 2;   // 0.79 MB
    P.stats = (float*)(ws + off); off += 3 * 2 * DIM * sizeof(float);
    P.cnt   = (int*)(ws + off); off += (size_t)NN * 4; off = (off + 255) & ~(size_t)255;
    P.slots = (int*)(ws + off); off += (size_t)NN * CAP * 4;                 // 5.12 MB
    (void)ws_size;

    k_prep<<<1024, 256, 0, stream>>>(P);
    k_bucket<<<(EE + 255) / 256, 256, 0, stream>>>(P);
    for (int L = 0; L < 3; ++L) {
        k_agg<<<NN / 4, 256, 0, stream>>>(P, L);
        k_gemm<<<NTILES, 256, 0, stream>>>(P, L);
    }
    k_norm<<<NN / 8, 256, 0, stream>>>(P);
}

// Round 10
// 224.218 us; speedup vs baseline: 5.0146x; 1.0775x over previous
//
#include <hip/hip_runtime.h>
#include <math.h>

#define NN 10000
#define EE 160000
#define DIM 256
#define KK 512            // concatenated K = 2*DIM
#define CAP 128           // bucket capacity (max deg ~45 for mean-16 degrees)
#define EPS_BN 1e-5f
#define AST 516           // LDS A-tile row stride in shorts (1032 B = 8B-aligned, 2-way banks)

typedef __attribute__((ext_vector_type(8)))  short bf16x8;
typedef __attribute__((ext_vector_type(16))) float f32x16;

union U16 { uint2 u2[2]; bf16x8 v; };

static __device__ __forceinline__ unsigned short f2bf(float f) {
    unsigned u = __float_as_uint(f);
    unsigned r = (u + 0x7fffu + ((u >> 16) & 1u)) >> 16;   // RTNE
    return (unsigned short)r;
}
static __device__ __forceinline__ float bflo(unsigned v) { return __uint_as_float(v << 16); }
static __device__ __forceinline__ float bfhi(unsigned v) { return __uint_as_float(v & 0xffff0000u); }
static __device__ __forceinline__ unsigned packbf(float a, float b) {
    return (unsigned)f2bf(a) | ((unsigned)f2bf(b) << 16);
}

struct Params {
    const float* x; const int* src; const int* dst;
    const float *Ws0, *Wn0, *Ws1, *Wn1, *Ws2, *Wn2;
    const float *g0, *be0, *g1, *be1, *g2, *be2;
    float* out;
    unsigned short* hx;     // [NN][DIM] bf16 x   (row = 32 uint4)
    unsigned short* z0;     // [NN][DIM] bf16 z ping
    unsigned short* z1;     // [NN][DIM] bf16 z pong
    unsigned short* wcat;   // [3][DIM][KK] bf16, [n][k]
    float* stats;           // [3][2*DIM]
    int* cnt;               // [NN]
    int* slots;             // [NN][CAP]
};

static __device__ __forceinline__ void accum8(float* a, uint4 v) {
    a[0] += bflo(v.x); a[1] += bfhi(v.x);
    a[2] += bflo(v.y); a[3] += bfhi(v.y);
    a[4] += bflo(v.z); a[5] += bfhi(v.z);
    a[6] += bflo(v.w); a[7] += bfhi(v.w);
}
static __device__ __forceinline__ void accum8n(float* a, uint4 v,
                                               const float* sc, const float* sh) {
    a[0] += fmaxf(bflo(v.x) * sc[0] + sh[0], 0.f);
    a[1] += fmaxf(bfhi(v.x) * sc[1] + sh[1], 0.f);
    a[2] += fmaxf(bflo(v.y) * sc[2] + sh[2], 0.f);
    a[3] += fmaxf(bfhi(v.y) * sc[3] + sh[3], 0.f);
    a[4] += fmaxf(bflo(v.z) * sc[4] + sh[4], 0.f);
    a[5] += fmaxf(bfhi(v.z) * sc[5] + sh[5], 0.f);
    a[6] += fmaxf(bflo(v.w) * sc[6] + sh[6], 0.f);
    a[7] += fmaxf(bfhi(v.w) * sc[7] + sh[7], 0.f);
}

// ---------------- prep: converts + zeroing ----------------
__global__ __launch_bounds__(256) void k_prep(Params P) {
    int g0 = blockIdx.x * 256 + threadIdx.x;
    int stride = gridDim.x * 256;
    for (int g = g0; g < NN * 64; g += stride) {            // x -> hx bf16 [NN][256]
        int r = g >> 6, c4 = (g & 63) * 4;
        float4 v = *(const float4*)(P.x + (size_t)r * DIM + c4);
        uint2 p; p.x = packbf(v.x, v.y); p.y = packbf(v.z, v.w);
        *(uint2*)(P.hx + (size_t)r * DIM + c4) = p;
    }
    for (int g = g0; g < 3 * DIM * KK; g += stride) {       // [Ws;Wn] -> wcat [n][k]
        int L = g >> 17; int i = g & 131071;
        int k = i >> 8, n = i & 255;
        const float* Ws = (L == 0) ? P.Ws0 : ((L == 1) ? P.Ws1 : P.Ws2);
        const float* Wn = (L == 0) ? P.Wn0 : ((L == 1) ? P.Wn1 : P.Wn2);
        float v = (k < DIM) ? Ws[(size_t)k * DIM + n] : Wn[(size_t)(k - DIM) * DIM + n];
        P.wcat[(size_t)L * DIM * KK + (size_t)n * KK + k] = f2bf(v);
    }
    for (int g = g0; g < NN + 6 * DIM; g += stride) {
        if (g < NN) P.cnt[g] = 0;
        else P.stats[g - NN] = 0.f;
    }
}

// ---------------- bucket build (R9-proven) ----------------
__global__ __launch_bounds__(256) void k_bucket(Params P) {
    int e = blockIdx.x * 256 + threadIdx.x;
    if (e < EE) {
        int d = P.dst[e];
        int p = atomicAdd(&P.cnt[d], 1);
        if (p < CAP) P.slots[(size_t)d * CAP + p] = P.src[e];
    }
}

// ---------------- fused agg + GEMM + stats, one layer ----------------
// grid = 313 x 512 threads (8 waves). Phase A: wave gathers 4 nodes (R9 k_agg
// body verbatim, direct sl[j] loads) into LDS A-tile [32][512] (+ own rows,
// BN+relu-normalized for L>0). Phase B: wave w = cols w*32..w*32+31, R9 k_gemm
// body verbatim with A from LDS. Ping-pong: gsrc != gdst always.
__global__ __launch_bounds__(512) void k_ag(Params P, int L,
                                            const unsigned short* __restrict__ gsrc,
                                            unsigned short* __restrict__ gdst) {
    __shared__ unsigned short At[32][AST];                  // 33 KB
    int t = threadIdx.x;
    int wave = t >> 6, lane = t & 63;
    int h = lane >> 5, l = lane & 31;

    float sc[8], sh[8];
    if (L > 0) {                                            // BN affine of prev layer
        const float* st = P.stats + (L - 1) * 2 * DIM;
        const float* gam = (L == 1) ? P.g0 : P.g1;
        const float* bet = (L == 1) ? P.be0 : P.be1;
#pragma unroll
        for (int i = 0; i < 8; ++i) {
            int c = l * 8 + i;
            float mu  = st[c] * (1.0f / NN);
            float var = st[DIM + c] * (1.0f / NN) - mu * mu;
            float k = rsqrtf(var + EPS_BN) * gam[c];
            sc[i] = k;
            sh[i] = bet[c] - mu * k;
        }
    }
    const uint4* srcm = (const uint4*)gsrc;                 // rows = 32 uint4

    // ================= phase A =================
    for (int i = 0; i < 4; ++i) {
        int m = wave * 4 + i;                               // 8 waves x 4 = 32 rows
        int node = blockIdx.x * 32 + m;
        unsigned short* arow = &At[m][0];
        if (node >= NN) {
            if (h == 0) {
                uint2 z2 = make_uint2(0u, 0u);
                *(uint2*)(arow + l * 8)           = z2;
                *(uint2*)(arow + l * 8 + 4)       = z2;
                *(uint2*)(arow + 256 + l * 8)     = z2;
                *(uint2*)(arow + 256 + l * 8 + 4) = z2;
            }
            continue;
        }
        int cnt = P.cnt[node]; if (cnt > CAP) cnt = CAP;
        const int* sl = P.slots + (size_t)node * CAP;
        if (h == 0) {                                       // own row -> A left half
            uint4 z = srcm[(size_t)node * 32 + l];
            uint4 o;
            if (L > 0) {
                o.x = packbf(fmaxf(bflo(z.x) * sc[0] + sh[0], 0.f),
                             fmaxf(bfhi(z.x) * sc[1] + sh[1], 0.f));
                o.y = packbf(fmaxf(bflo(z.y) * sc[2] + sh[2], 0.f),
                             fmaxf(bfhi(z.y) * sc[3] + sh[3], 0.f));
                o.z = packbf(fmaxf(bflo(z.z) * sc[4] + sh[4], 0.f),
                             fmaxf(bfhi(z.z) * sc[5] + sh[5], 0.f));
                o.w = packbf(fmaxf(bflo(z.w) * sc[6] + sh[6], 0.f),
                             fmaxf(bfhi(z.w) * sc[7] + sh[7], 0.f));
            } else o = z;
            *(uint2*)(arow + l * 8)     = make_uint2(o.x, o.y);
            *(uint2*)(arow + l * 8 + 4) = make_uint2(o.z, o.w);
        }
        float a[8] = {0, 0, 0, 0, 0, 0, 0, 0};
        int j = h;                                          // half-waves interleave edges
        if (L == 0) {
            for (; j + 6 < cnt; j += 8) {
                int i0 = sl[j],     i1 = sl[j + 2];
                int i2 = sl[j + 4], i3 = sl[j + 6];
                uint4 v0 = srcm[(size_t)i0 * 32 + l];
                uint4 v1 = srcm[(size_t)i1 * 32 + l];
                uint4 v2 = srcm[(size_t)i2 * 32 + l];
                uint4 v3 = srcm[(size_t)i3 * 32 + l];
                accum8(a, v0); accum8(a, v1); accum8(a, v2); accum8(a, v3);
            }
            for (; j < cnt; j += 2) accum8(a, srcm[(size_t)sl[j] * 32 + l]);
        } else {
            for (; j + 6 < cnt; j += 8) {
                int i0 = sl[j],     i1 = sl[j + 2];
                int i2 = sl[j + 4], i3 = sl[j + 6];
                uint4 v0 = srcm[(size_t)i0 * 32 + l];
                uint4 v1 = srcm[(size_t)i1 * 32 + l];
                uint4 v2 = srcm[(size_t)i2 * 32 + l];
                uint4 v3 = srcm[(size_t)i3 * 32 + l];
                accum8n(a, v0, sc, sh); accum8n(a, v1, sc, sh);
                accum8n(a, v2, sc, sh); accum8n(a, v3, sc, sh);
            }
            for (; j < cnt; j += 2) accum8n(a, srcm[(size_t)sl[j] * 32 + l], sc, sh);
        }
#pragma unroll
        for (int q = 0; q < 8; ++q) a[q] += __shfl_xor(a[q], 32);
        if (h == 0) {                                       // mean -> A right half
            float inv = 1.0f / (float)(cnt > 1 ? cnt : 1);
            *(uint2*)(arow + 256 + l * 8)     = make_uint2(packbf(a[0] * inv, a[1] * inv),
                                                           packbf(a[2] * inv, a[3] * inv));
            *(uint2*)(arow + 256 + l * 8 + 4) = make_uint2(packbf(a[4] * inv, a[5] * inv),
                                                           packbf(a[6] * inv, a[7] * inv));
        }
    }
    __syncthreads();

    // ================= phase B (R9 k_gemm body; A from LDS) =================
    const unsigned short* wcatL = P.wcat + (size_t)L * DIM * KK;
    float* statsL = P.stats + L * 2 * DIM;
    int m = l;
    int row0 = blockIdx.x * 32;
    int colw0 = wave * 32;                                  // 8 waves x 32 = 256 cols
    const unsigned short* Bp = wcatL + (size_t)(colw0 + m) * KK + h * 8;
    const unsigned short* Arow = &At[m][0];
    f32x16 acc;
#pragma unroll
    for (int i = 0; i < 16; ++i) acc[i] = 0.f;
#pragma unroll 8
    for (int k0 = 0; k0 < KK; k0 += 16) {
        U16 ua;
        ua.u2[0] = *(const uint2*)(Arow + k0 + h * 8);
        ua.u2[1] = *(const uint2*)(Arow + k0 + h * 8 + 4);
        bf16x8 av = ua.v;
        bf16x8 bv = *(const bf16x8*)(Bp + k0);
        acc = __builtin_amdgcn_mfma_f32_32x32x16_bf16(av, bv, acc, 0, 0, 0);
    }
    int cc = colw0 + m;
    float s = 0.f, s2 = 0.f;
#pragma unroll
    for (int reg = 0; reg < 16; ++reg) {
        int r = row0 + (reg & 3) + 8 * (reg >> 2) + 4 * h;
        if (r < NN) {
            float v = acc[reg];
            gdst[(size_t)r * DIM + cc] = f2bf(v);
            s += v; s2 += v * v;
        }
    }
    s  += __shfl_down(s, 32);
    s2 += __shfl_down(s2, 32);
    if (h == 0) {
        atomicAdd(&statsL[cc], s);
        atomicAdd(&statsL[DIM + cc], s2);
    }
}

// ---------------- final BN + sigmoid -> out (R9 body) ----------------
__global__ __launch_bounds__(256) void k_norm(Params P) {
    const float* statsL = P.stats + 2 * 2 * DIM;
    int t = threadIdx.x;
    int c8 = (t & 31) * 8;
    int r = blockIdx.x * 8 + (t >> 5);                      // grid 1250
    float sc[8], sh[8];
#pragma unroll
    for (int i = 0; i < 8; ++i) {
        int c = c8 + i;
        float mu  = statsL[c] * (1.0f / NN);
        float var = statsL[DIM + c] * (1.0f / NN) - mu * mu;
        float k = rsqrtf(var + EPS_BN) * P.g2[c];
        sc[i] = k;
        sh[i] = P.be2[c] - mu * k;
    }
    uint4 v = *(const uint4*)(P.z0 + (size_t)r * DIM + c8);
    float f[8] = {bflo(v.x), bfhi(v.x), bflo(v.y), bfhi(v.y),
                  bflo(v.z), bfhi(v.z), bflo(v.w), bfhi(v.w)};
#pragma unroll
    for (int i = 0; i < 8; ++i) f[i] = f[i] * sc[i] + sh[i];
    float4 o0, o1;
    o0.x = 1.0f / (1.0f + __expf(-f[0]));
    o0.y = 1.0f / (1.0f + __expf(-f[1]));
    o0.z = 1.0f / (1.0f + __expf(-f[2]));
    o0.w = 1.0f / (1.0f + __expf(-f[3]));
    o1.x = 1.0f / (1.0f + __expf(-f[4]));
    o1.y = 1.0f / (1.0f + __expf(-f[5]));
    o1.z = 1.0f / (1.0f + __expf(-f[6]));
    o1.w = 1.0f / (1.0f + __expf(-f[7]));
    *(float4*)(P.out + (size_t)r * DIM + c8)     = o0;
    *(float4*)(P.out + (size_t)r * DIM + c8 + 4) = o1;
}

extern "C" void kernel_launch(void* const* d_in, const int* in_sizes, int n_in,
                              void* d_out, int out_size, void* d_ws, size_t ws_size,
                              hipStream_t stream) {
    Params P;
    P.x   = (const float*)d_in[0];
    P.src = (const int*)d_in[1];
    P.dst = (const int*)d_in[2];
    P.Ws0 = (const float*)d_in[3];  P.Wn0 = (const float*)d_in[4];
    P.g0  = (const float*)d_in[6];  P.be0 = (const float*)d_in[7];
    P.Ws1 = (const float*)d_in[8];  P.Wn1 = (const float*)d_in[9];
    P.g1  = (const float*)d_in[11]; P.be1 = (const float*)d_in[12];
    P.Ws2 = (const float*)d_in[13]; P.Wn2 = (const float*)d_in[14];
    P.g2  = (const float*)d_in[16]; P.be2 = (const float*)d_in[17];
    P.out = (float*)d_out;

    char* ws = (char*)d_ws;
    size_t off = 0;
    P.hx   = (unsigned short*)(ws + off); off += (size_t)NN * DIM * 2;       // 5.12 MB
    P.z0   = (unsigned short*)(ws + off); off += (size_t)NN * DIM * 2;       // 5.12 MB
    P.z1   = (unsigned short*)(ws + off); off += (size_t)NN * DIM * 2;       // 5.12 MB
    P.wcat = (unsigned short*)(ws + off); off += (size_t)3 * DIM * KK * 2;   // 0.79 MB
    P.stats = (float*)(ws + off); off += 3 * 2 * DIM * sizeof(float);
    P.cnt   = (int*)(ws + off); off += (size_t)NN * 4; off = (off + 255) & ~(size_t)255;
    P.slots = (int*)(ws + off); off += (size_t)NN * CAP * 4;                 // 5.12 MB
    (void)ws_size;

    k_prep<<<512, 256, 0, stream>>>(P);
    k_bucket<<<(EE + 255) / 256, 256, 0, stream>>>(P);
    // ping-pong: L0 hx->z0, L1 z0->z1, L2 z1->z0 (gather src != gemm dst)
    k_ag<<<313, 512, 0, stream>>>(P, 0, P.hx, P.z0);
    k_ag<<<313, 512, 0, stream>>>(P, 1, P.z0, P.z1);
    k_ag<<<313, 512, 0, stream>>>(P, 2, P.z1, P.z0);
    k_norm<<<NN / 8, 256, 0, stream>>>(P);
}